// Round 28
// baseline (29.558 us; speedup 1.0000x reference)
//
#include <hip/hip_runtime.h>
#include <hip/hip_bf16.h>

#define NB 32
#define SEQ 1024
#define DIM 64
#define LDP 72   // padded LDS stride: 144B rows, 16B-aligned (qkv only)

typedef __attribute__((ext_vector_type(8))) short bf16x8;
typedef __attribute__((ext_vector_type(4))) short bf16x4;
typedef __attribute__((ext_vector_type(8))) unsigned short ushort8;
typedef __attribute__((ext_vector_type(4))) float f32x4;
typedef unsigned long long ull;

#define MFMA16 __builtin_amdgcn_mfma_f32_16x16x32_bf16
#define MFMA16K __builtin_amdgcn_mfma_f32_16x16x16bf16_1k

// async global->LDS DMA, 16B per lane, linear LDS dest (wave base + lane*16)
#define GLL(gp, lp) __builtin_amdgcn_global_load_lds( \
    (const __attribute__((address_space(1))) void*)(gp), \
    (__attribute__((address_space(3))) void*)(lp), 16, 0, 0)

#define DEFER_THR 8.0f

__device__ __forceinline__ unsigned short f2bf(float f) {
    union { float f; unsigned u; } c; c.f = f;
    return (unsigned short)((c.u + 0x7FFFu + ((c.u >> 16) & 1u)) >> 16);  // RNE
}
__device__ __forceinline__ float bf2f(unsigned short u) {
    union { unsigned u; float f; } c; c.u = (unsigned)u << 16;
    return c.f;
}
__device__ __forceinline__ unsigned pk2(float a, float b) {
    return (unsigned)f2bf(a) | ((unsigned)f2bf(b) << 16);
}
__device__ __forceinline__ bf16x8 cvt8(float4 a, float4 b) {
    bf16x8 r;
    r[0] = (short)f2bf(a.x); r[1] = (short)f2bf(a.y);
    r[2] = (short)f2bf(a.z); r[3] = (short)f2bf(a.w);
    r[4] = (short)f2bf(b.x); r[5] = (short)f2bf(b.y);
    r[6] = (short)f2bf(b.z); r[7] = (short)f2bf(b.w);
    return r;
}

// LPT dispatch order for 24 chunks/batch (chunk=8 decode below), sorted by
// descending chain length: 10x len-8, then 7,7,6,6,5,5,4,4,3,3,2,2,1,1.
__device__ const int kOrder[24] = {
    7, 8, 10, 12, 14, 16, 18, 20, 22, 23,
    6, 21, 5, 19, 4, 17, 3, 15, 2, 13, 1, 11, 0, 9
};

// ---------------- Kernel 1: QKV projection, fragment-native stores ---------
__global__ __launch_bounds__(256) void qkv_proj(
    const float* __restrict__ x, const float* __restrict__ Wq,
    const float* __restrict__ Wk, const float* __restrict__ Wv,
    unsigned short* __restrict__ qg, unsigned short* __restrict__ kg,
    unsigned short* __restrict__ vtg)
{
    __shared__ unsigned short ws[3][64 * LDP];
    const int tid = threadIdx.x;
    const int w = tid >> 6, lane = tid & 63;
    const int l15 = lane & 15, l4 = lane >> 4;
    const int orig = blockIdx.x;
    const int blkid = (orig & 7) * 64 + (orig >> 3);  // XCD-chunked, bijective
    const size_t row0 = (size_t)blkid * 64;

    {   // stage W matrices as bf16 (padded rows)
        const int r = tid >> 2, c = (tid & 3) * 16;
        const float* srcs[3] = {Wq, Wk, Wv};
        #pragma unroll
        for (int m = 0; m < 3; ++m) {
            const float* s = srcs[m] + r * DIM + c;
            const float4 f0 = ((const float4*)s)[0], f1 = ((const float4*)s)[1];
            const float4 f2 = ((const float4*)s)[2], f3 = ((const float4*)s)[3];
            *(bf16x8*)&ws[m][r * LDP + c]     = cvt8(f0, f1);
            *(bf16x8*)&ws[m][r * LDP + c + 8] = cvt8(f2, f3);
        }
    }
    const float* xp = x + (row0 + w * 16 + l15) * DIM + l4 * 8;
    const float4 x0 = ((const float4*)xp)[0];
    const float4 x1 = ((const float4*)xp)[1];
    const float4 x2 = ((const float4*)(xp + 32))[0];
    const float4 x3 = ((const float4*)(xp + 32))[1];
    const bf16x8 xa0 = cvt8(x0, x1), xa1 = cvt8(x2, x3);
    __syncthreads();

    const size_t bidx = row0 >> 10;
    const int s0 = (int)(row0 & 1023);
    const size_t qkrow = (row0 + w * 16 + l15) * DIM + l4 * 4;

    #pragma unroll
    for (int nb = 0; nb < 4; ++nb) {
        const int off = (nb * 16 + l15) * LDP + l4 * 8;
        {   // q: swapped C = Wq . X^T -> lane holds 4 consecutive d
            const bf16x8 b0 = *(const bf16x8*)&ws[0][off];
            const bf16x8 b1 = *(const bf16x8*)&ws[0][off + 32];
            f32x4 a = {0.f, 0.f, 0.f, 0.f};
            a = MFMA16(b0, xa0, a, 0, 0, 0);
            a = MFMA16(b1, xa1, a, 0, 0, 0);
            const ull v = (ull)pk2(a[0] * 0.125f, a[1] * 0.125f) |
                          ((ull)pk2(a[2] * 0.125f, a[3] * 0.125f) << 32);
            *(ull*)&qg[qkrow + nb * 16] = v;
        }
        {   // k: swapped, no scale
            const bf16x8 b0 = *(const bf16x8*)&ws[1][off];
            const bf16x8 b1 = *(const bf16x8*)&ws[1][off + 32];
            f32x4 a = {0.f, 0.f, 0.f, 0.f};
            a = MFMA16(b0, xa0, a, 0, 0, 0);
            a = MFMA16(b1, xa1, a, 0, 0, 0);
            const ull v = (ull)pk2(a[0], a[1]) | ((ull)pk2(a[2], a[3]) << 32);
            *(ull*)&kg[qkrow + nb * 16] = v;
        }
        {   // vT: normal order -> lane holds 4 consecutive s
            const bf16x8 b0 = *(const bf16x8*)&ws[2][off];
            const bf16x8 b1 = *(const bf16x8*)&ws[2][off + 32];
            f32x4 a = {0.f, 0.f, 0.f, 0.f};
            a = MFMA16(xa0, b0, a, 0, 0, 0);
            a = MFMA16(xa1, b1, a, 0, 0, 0);
            const ull v = (ull)pk2(a[0], a[1]) | ((ull)pk2(a[2], a[3]) << 32);
            *(ull*)&vtg[(bidx * 64 + nb * 16 + l15) * SEQ + s0 + w * 16 + l4 * 4] = v;
        }
    }
}

// ---------------- Kernel 2: split-K flash attention partial ----------------
// Round-21 structure (chunk=8, DMA dbuf, 1 barrier/tile, exact LPT,
// defer-max, deferred l). CHANGE: PV uses K=16 MFMA (16x16x16_bf16) so the
// softmax C-fragment (4 consecutive k per lane) IS the A-fragment -- the
// per-tile P LDS round-trip is deleted. V read as 16x ds_read_b64.
__global__ __launch_bounds__(256, 4) void attn_partial(
    const unsigned short* __restrict__ qg, const unsigned short* __restrict__ kg,
    const unsigned short* __restrict__ vtg, float* __restrict__ out,
    unsigned short* __restrict__ part_acc, float* __restrict__ part_ml)
{
    __shared__ unsigned short Ks[2][64 * 64];
    __shared__ unsigned short Vs[2][64 * 64];

    const int tid = threadIdx.x;
    const int w = tid >> 6, lane = tid & 63;
    const int l15 = lane & 15, l4 = lane >> 4;

    const int orig = blockIdx.x;
    const int blk = (orig & 7) * 96 + (orig >> 3);  // 768 = 8*96, bijective
    const int b = blk / 24;
    const int c = kOrder[blk % 24];      // exact LPT: longest chains first
    int qt, ch, nch;                     // chunk decode (24 chunks per batch)
    if (c < 8) { qt = c;                ch = 0;           nch = 1; }
    else       { qt = 8 + ((c - 8) >> 1); ch = (c - 8) & 1; nch = 2; }
    const int q0 = qt * 64;
    const int t0 = ch * 8;
    const int t1 = min(t0 + 8, qt + 1);

    // Q fragments (B-operand), scale pre-folded
    const unsigned short* qp = qg + ((size_t)(b * SEQ + q0 + w * 16 + l15)) * DIM + l4 * 8;
    const bf16x8 qf0 = *(const bf16x8*)qp;
    const bf16x8 qf1 = *(const bf16x8*)(qp + 32);

    // DMA staging: lane l of wave w covers stored row w*16+i*8+(l>>3),
    // stored chunk l&7. Inverse-swizzled global chunk = (l&7)^(l>>3).
    const int lrow = lane >> 3;
    const int gch  = (lane & 7) ^ lrow;
    const unsigned short* kgl0 = kg + (size_t)b * SEQ * DIM
                               + (size_t)(w * 16 + lrow) * DIM + gch * 8;
    const unsigned short* kgl1 = kgl0 + (size_t)8 * DIM;
    const unsigned short* vgl0 = vtg + ((size_t)b * 64 + w * 16 + lrow) * SEQ + gch * 8;
    const unsigned short* vgl1 = vgl0 + (size_t)8 * SEQ;
    const int ldsb0 = (w * 16) * 64;
    const int ldsb1 = (w * 16 + 8) * 64;

    // read-side swizzled chunk offset (row&7 == l15&7 for all frag rows)
    const int rc0 = (l4 ^ (l15 & 7)) << 3;

    // prologue: DMA tile t0 into buffer 0
    {
        const size_t ko = (size_t)t0 * 64 * DIM;
        const size_t vo = (size_t)t0 * 64;
        GLL(kgl0 + ko, &Ks[0][ldsb0]);
        GLL(kgl1 + ko, &Ks[0][ldsb1]);
        GLL(vgl0 + vo, &Vs[0][ldsb0]);
        GLL(vgl1 + vo, &Vs[0][ldsb1]);
    }
    __syncthreads();   // drains vmcnt: tile t0 resident

    f32x4 acc[4] = {};
    float m_run = -1e30f;   // running max (uniform across the l4 group)
    float l_part = 0.f;     // per-lane partial of l (own 16 k-values)

    for (int tt = t0; tt < t1; ++tt) {
        const int cur = (tt - t0) & 1;
        const bool pf = (tt + 1 < t1);
        if (pf) {  // fire-and-forget DMA for t+1; lands during this tile
            const size_t ko = (size_t)(tt + 1) * 64 * DIM;
            const size_t vo = (size_t)(tt + 1) * 64;
            const int nxt = cur ^ 1;
            GLL(kgl0 + ko, &Ks[nxt][ldsb0]);
            GLL(kgl1 + ko, &Ks[nxt][ldsb1]);
            GLL(vgl0 + vo, &Vs[nxt][ldsb0]);
            GLL(vgl1 + vo, &Vs[nxt][ldsb1]);
        }

        // S^T = K . Q : lane holds S[k=nb*16+l4*4+r][q=l15]
        f32x4 s[4];
        __builtin_amdgcn_s_setprio(1);
        #pragma unroll
        for (int nb = 0; nb < 4; ++nb) {
            const int krow = (nb * 16 + l15) * 64;
            const bf16x8 kf0 = *(const bf16x8*)&Ks[cur][krow + rc0];
            const bf16x8 kf1 = *(const bf16x8*)&Ks[cur][krow + (rc0 ^ 32)];
            f32x4 sv = {0.f, 0.f, 0.f, 0.f};
            sv = MFMA16(kf0, qf0, sv, 0, 0, 0);
            sv = MFMA16(kf1, qf1, sv, 0, 0, 0);
            s[nb] = sv;
        }
        __builtin_amdgcn_s_setprio(0);

        if (tt == qt) {  // causal mask on diagonal tile
            const int qabs = q0 + w * 16 + l15;
            #pragma unroll
            for (int nb = 0; nb < 4; ++nb)
                #pragma unroll
                for (int r = 0; r < 4; ++r)
                    if (tt * 64 + nb * 16 + l4 * 4 + r > qabs) s[nb][r] = -1e30f;
        }

        // local pmax (this lane's 16 values) -- pure tree, no shfl
        float pmax = fmaxf(fmaxf(fmaxf(s[0][0], s[0][1]), fmaxf(s[0][2], s[0][3])),
                           fmaxf(fmaxf(s[1][0], s[1][1]), fmaxf(s[1][2], s[1][3])));
        pmax = fmaxf(pmax,
               fmaxf(fmaxf(fmaxf(s[2][0], s[2][1]), fmaxf(s[2][2], s[2][3])),
                     fmaxf(fmaxf(s[3][0], s[3][1]), fmaxf(s[3][2], s[3][3]))));

        // defer-max (T13): rescale only when some lane's local max grew past
        // THR. Butterfly to the true row max only inside the rare branch.
        if (!__all(pmax - m_run <= DEFER_THR)) {
            pmax = fmaxf(pmax, __shfl_xor(pmax, 16));
            pmax = fmaxf(pmax, __shfl_xor(pmax, 32));
            const float mnew = fmaxf(m_run, pmax);
            const float scf = __expf(m_run - mnew);
            m_run = mnew;
            l_part *= scf;
            #pragma unroll
            for (int r = 0; r < 4; ++r) {  // acc row r = q-row l4*4+r
                const float srw = __shfl(scf, l4 * 4 + r);
                acc[0][r] *= srw; acc[1][r] *= srw;
                acc[2][r] *= srw; acc[3][r] *= srw;
            }
        }

        #pragma unroll
        for (int nb = 0; nb < 4; ++nb)
            #pragma unroll
            for (int r = 0; r < 4; ++r) {
                s[nb][r] = __expf(s[nb][r] - m_run);
                l_part += s[nb][r];
            }

        // P -> bf16 A-fragments IN REGISTERS (K=16 A-frag == C-frag quad)
        bf16x4 paf[4];
        #pragma unroll
        for (int ks = 0; ks < 4; ++ks) {
            paf[ks][0] = (short)f2bf(s[ks][0]);
            paf[ks][1] = (short)f2bf(s[ks][1]);
            paf[ks][2] = (short)f2bf(s[ks][2]);
            paf[ks][3] = (short)f2bf(s[ks][3]);
        }

        // O += P . V via 16x16x16 MFMA: B-frag lane holds V[k=l4*4+j][d=l15]
        // = Vs[d row][k], 8B reads with the same XOR chunk swizzle.
        __builtin_amdgcn_s_setprio(1);
        #pragma unroll
        for (int nb2 = 0; nb2 < 4; ++nb2) {
            const int vrow = (nb2 * 16 + l15) * 64;
            const int sub = (l4 & 1) * 4;
            #pragma unroll
            for (int ks = 0; ks < 4; ++ks) {
                const int chk = (ks * 2 + (l4 >> 1)) ^ (l15 & 7);
                const bf16x4 vb = *(const bf16x4*)&Vs[cur][vrow + (chk << 3) + sub];
                acc[nb2] = MFMA16K(paf[ks], vb, acc[nb2], 0, 0, 0);
            }
        }
        __builtin_amdgcn_s_setprio(0);

        __syncthreads();  // single barrier per tile; also drains t+1 DMA
    }

    // finalize l: butterfly the per-lane partials once (uniform across l4)
    float l_run = l_part;
    l_run += __shfl_xor(l_run, 16);
    l_run += __shfl_xor(l_run, 32);

    if (nch == 1) {  // qt <= 7: full k-range done here, write final output
        const float inv = 1.0f / l_run;
        #pragma unroll
        for (int r = 0; r < 4; ++r) {
            const float ir = __shfl(inv, l4 * 4 + r);
            const size_t row = (size_t)(b * SEQ + q0 + w * 16 + l4 * 4 + r);
            #pragma unroll
            for (int nb2 = 0; nb2 < 4; ++nb2)
                out[row * DIM + nb2 * 16 + l15] = acc[nb2][r] * ir;
        }
    } else {         // lane-native partial: 2 coalesced bf16x8 stores
        const size_t slot = (size_t)((b * 8 + (qt - 8)) * 2 + ch);
        unsigned short* pa = part_acc + slot * 4096 + (size_t)(w * 64 + lane) * 16;
        bf16x8 o0, o1;
        #pragma unroll
        for (int nb2 = 0; nb2 < 2; ++nb2)
            #pragma unroll
            for (int r = 0; r < 4; ++r) {
                o0[nb2 * 4 + r] = (short)f2bf(acc[nb2][r]);
                o1[nb2 * 4 + r] = (short)f2bf(acc[nb2 + 2][r]);
            }
        *(bf16x8*)pa       = o0;
        *(bf16x8*)(pa + 8) = o1;
        if (l4 == 0) {
            float* pm = part_ml + slot * 128;
            pm[w * 16 + l15]      = m_run;
            pm[64 + w * 16 + l15] = l_run;
        }
    }
}

// ---------------- Kernel 3: split-K combine (qt >= 8, exactly 2 chunks) ----
__global__ __launch_bounds__(256) void combine(
    const unsigned short* __restrict__ part_acc,
    const float* __restrict__ part_ml, float* __restrict__ out)
{
    const int orig = blockIdx.x;
    const int blk = (orig & 7) * 32 + (orig >> 3);   // 256 = 8*32, bijective
    const int b = blk / 8, qt8 = blk % 8;
    const int qt = qt8 + 8;
    const int tid = threadIdx.x;
    const int w2 = tid >> 6, lane = tid & 63;
    const int l15 = lane & 15, l4 = lane >> 4;
    const size_t base0 = (size_t)(b * 8 + qt8) * 2;

    float mv[2][4], lv[2][4], M[4];
    #pragma unroll
    for (int cc = 0; cc < 2; ++cc) {
        const float* pm = part_ml + (base0 + cc) * 128;
        #pragma unroll
        for (int r = 0; r < 4; ++r) {
            mv[cc][r] = pm[w2 * 16 + l4 * 4 + r];
            lv[cc][r] = pm[64 + w2 * 16 + l4 * 4 + r];
        }
    }
    #pragma unroll
    for (int r = 0; r < 4; ++r) M[r] = fmaxf(mv[0][r], mv[1][r]);

    float o[16], L[4];
    #pragma unroll
    for (int i = 0; i < 16; ++i) o[i] = 0.f;
    #pragma unroll
    for (int r = 0; r < 4; ++r) L[r] = 0.f;
    #pragma unroll
    for (int cc = 0; cc < 2; ++cc) {
        float wsc[4];
        #pragma unroll
        for (int r = 0; r < 4; ++r) {
            wsc[r] = __expf(mv[cc][r] - M[r]);
            L[r] += wsc[r] * lv[cc][r];
        }
        const unsigned short* pa =
            part_acc + (base0 + cc) * 4096 + (size_t)(w2 * 64 + lane) * 16;
        const ushort8 t0 = *(const ushort8*)pa;
        const ushort8 t1 = *(const ushort8*)(pa + 8);
        #pragma unroll
        for (int i = 0; i < 8; ++i) {
            o[i]     += wsc[i & 3] * bf2f(t0[i]);
            o[i + 8] += wsc[i & 3] * bf2f(t1[i]);
        }
    }
    float inv[4];
    #pragma unroll
    for (int r = 0; r < 4; ++r) inv[r] = 1.0f / L[r];
    #pragma unroll
    for (int nb2 = 0; nb2 < 4; ++nb2)
        #pragma unroll
        for (int r = 0; r < 4; ++r) {
            const size_t row = (size_t)(b * SEQ + qt * 64 + w2 * 16 + l4 * 4 + r);
            out[row * DIM + nb2 * 16 + l15] = o[nb2 * 4 + r] * inv[r];
        }
}

extern "C" void kernel_launch(void* const* d_in, const int* in_sizes, int n_in,
                              void* d_out, int out_size, void* d_ws, size_t ws_size,
                              hipStream_t stream) {
    const float* x  = (const float*)d_in[0];
    const float* Wq = (const float*)d_in[1];
    const float* Wk = (const float*)d_in[2];
    const float* Wv = (const float*)d_in[3];
    float* outp = (float*)d_out;

    // ws: q | k | vT (bf16, 4MB each) | part_acc (bf16, 4.2MB) | part_ml (fp32)
    unsigned short* qw  = (unsigned short*)d_ws;
    unsigned short* kw  = qw + (size_t)NB * SEQ * DIM;
    unsigned short* vtw = kw + (size_t)NB * SEQ * DIM;
    unsigned short* pacc = vtw + (size_t)NB * SEQ * DIM;
    float* pml = (float*)(pacc + (size_t)NB * 8 * 2 * 4096);

    qkv_proj<<<NB * SEQ / 64, 256, 0, stream>>>(x, Wq, Wk, Wv, qw, kw, vtw);
    attn_partial<<<NB * 24, 256, 0, stream>>>(qw, kw, vtw, outp, pacc, pml);
    combine<<<NB * 8, 256, 0, stream>>>(pacc, pml, outp);
}

// Round 29
// 28.162 us; speedup vs baseline: 1.0496x; 1.0496x over previous
//
#include <hip/hip_runtime.h>
#include <hip/hip_bf16.h>

#define NB 32
#define SEQ 1024
#define DIM 64
#define LDP 72   // padded LDS stride: 144B rows, 16B-aligned (qkv only)

typedef __attribute__((ext_vector_type(8))) short bf16x8;
typedef __attribute__((ext_vector_type(8))) unsigned short ushort8;
typedef __attribute__((ext_vector_type(4))) float f32x4;
typedef unsigned long long ull;

#define MFMA16 __builtin_amdgcn_mfma_f32_16x16x32_bf16

// async global->LDS DMA, 16B per lane, linear LDS dest (wave base + lane*16)
#define GLL(gp, lp) __builtin_amdgcn_global_load_lds( \
    (const __attribute__((address_space(1))) void*)(gp), \
    (__attribute__((address_space(3))) void*)(lp), 16, 0, 0)

#define DEFER_THR 8.0f

__device__ __forceinline__ unsigned short f2bf(float f) {
    union { float f; unsigned u; } c; c.f = f;
    return (unsigned short)((c.u + 0x7FFFu + ((c.u >> 16) & 1u)) >> 16);  // RNE
}
__device__ __forceinline__ float bf2f(unsigned short u) {
    union { unsigned u; float f; } c; c.u = (unsigned)u << 16;
    return c.f;
}
__device__ __forceinline__ unsigned pk2(float a, float b) {
    return (unsigned)f2bf(a) | ((unsigned)f2bf(b) << 16);
}
__device__ __forceinline__ bf16x8 cvt8(float4 a, float4 b) {
    bf16x8 r;
    r[0] = (short)f2bf(a.x); r[1] = (short)f2bf(a.y);
    r[2] = (short)f2bf(a.z); r[3] = (short)f2bf(a.w);
    r[4] = (short)f2bf(b.x); r[5] = (short)f2bf(b.y);
    r[6] = (short)f2bf(b.z); r[7] = (short)f2bf(b.w);
    return r;
}

// LPT dispatch order for 24 chunks/batch (chunk=8 decode below), sorted by
// descending chain length: 10x len-8, then 7,7,6,6,5,5,4,4,3,3,2,2,1,1.
__device__ const int kOrder[24] = {
    7, 8, 10, 12, 14, 16, 18, 20, 22, 23,
    6, 21, 5, 19, 4, 17, 3, 15, 2, 13, 1, 11, 0, 9
};

// ---------------- Kernel 1: QKV projection (round-15/21 version) -----------
__global__ __launch_bounds__(256) void qkv_proj(
    const float* __restrict__ x, const float* __restrict__ Wq,
    const float* __restrict__ Wk, const float* __restrict__ Wv,
    unsigned short* __restrict__ qg, unsigned short* __restrict__ kg,
    unsigned short* __restrict__ vtg)
{
    __shared__ unsigned short ws[3][64 * LDP];
    __shared__ unsigned short tr[3][64 * LDP];
    const int tid = threadIdx.x;
    const int w = tid >> 6, lane = tid & 63;
    const int l15 = lane & 15, l4 = lane >> 4;
    const int orig = blockIdx.x;
    const int blkid = (orig & 7) * 64 + (orig >> 3);  // XCD-chunked, bijective
    const size_t row0 = (size_t)blkid * 64;

    {   // stage W matrices as bf16 (padded rows)
        const int r = tid >> 2, c = (tid & 3) * 16;
        const float* srcs[3] = {Wq, Wk, Wv};
        #pragma unroll
        for (int m = 0; m < 3; ++m) {
            const float* s = srcs[m] + r * DIM + c;
            const float4 f0 = ((const float4*)s)[0], f1 = ((const float4*)s)[1];
            const float4 f2 = ((const float4*)s)[2], f3 = ((const float4*)s)[3];
            *(bf16x8*)&ws[m][r * LDP + c]     = cvt8(f0, f1);
            *(bf16x8*)&ws[m][r * LDP + c + 8] = cvt8(f2, f3);
        }
    }
    const float* xp = x + (row0 + w * 16 + l15) * DIM + l4 * 8;
    const float4 x0 = ((const float4*)xp)[0];
    const float4 x1 = ((const float4*)xp)[1];
    const float4 x2 = ((const float4*)(xp + 32))[0];
    const float4 x3 = ((const float4*)(xp + 32))[1];
    const bf16x8 xa0 = cvt8(x0, x1), xa1 = cvt8(x2, x3);
    __syncthreads();

    #pragma unroll
    for (int m = 0; m < 3; ++m) {
        #pragma unroll
        for (int nb = 0; nb < 4; ++nb) {
            const bf16x8 b0 = *(const bf16x8*)&ws[m][(nb * 16 + l15) * LDP + l4 * 8];
            const bf16x8 b1 = *(const bf16x8*)&ws[m][(nb * 16 + l15) * LDP + 32 + l4 * 8];
            f32x4 a = {0.f, 0.f, 0.f, 0.f};
            a = MFMA16(xa0, b0, a, 0, 0, 0);
            a = MFMA16(xa1, b1, a, 0, 0, 0);
            #pragma unroll
            for (int r = 0; r < 4; ++r) {
                const int orow = w * 16 + l4 * 4 + r, ocol = nb * 16 + l15;
                const float v = (m == 0) ? a[r] * 0.125f : a[r];
                if (m == 2) tr[2][ocol * LDP + orow] = f2bf(v);  // v transposed
                else        tr[m][orow * LDP + ocol] = f2bf(v);
            }
        }
    }
    __syncthreads();
    {   // fully-coalesced stores
        const int r = tid >> 2, c = (tid & 3) * 16;
        const size_t b = row0 >> 10; const int s0 = (int)(row0 & 1023);
        unsigned short* qdst = qg + (row0 + r) * DIM + c;
        *(bf16x8*)qdst       = *(const bf16x8*)&tr[0][r * LDP + c];
        *(bf16x8*)(qdst + 8) = *(const bf16x8*)&tr[0][r * LDP + c + 8];
        unsigned short* kdst = kg + (row0 + r) * DIM + c;
        *(bf16x8*)kdst       = *(const bf16x8*)&tr[1][r * LDP + c];
        *(bf16x8*)(kdst + 8) = *(const bf16x8*)&tr[1][r * LDP + c + 8];
        unsigned short* vdst = vtg + (b * 64 + r) * SEQ + s0 + c;
        *(bf16x8*)vdst       = *(const bf16x8*)&tr[2][r * LDP + c];
        *(bf16x8*)(vdst + 8) = *(const bf16x8*)&tr[2][r * LDP + c + 8];
    }
}

// ---------------- Kernel 2: split-K flash attention partial ----------------
// Best-measured config (round 21, 28.19us): chunk=8, DMA dbuf, 1 barrier/
// tile, exact LPT, defer-max with local-pmax check, deferred per-lane l,
// P relayout via wave-private swizzled LDS + K=32 MFMA PV.
__global__ __launch_bounds__(256, 4) void attn_partial(
    const unsigned short* __restrict__ qg, const unsigned short* __restrict__ kg,
    const unsigned short* __restrict__ vtg, float* __restrict__ out,
    unsigned short* __restrict__ part_acc, float* __restrict__ part_ml)
{
    __shared__ unsigned short Ks[2][64 * 64];
    __shared__ unsigned short Vs[2][64 * 64];
    __shared__ unsigned short Ps[4][16 * 64];

    const int tid = threadIdx.x;
    const int w = tid >> 6, lane = tid & 63;
    const int l15 = lane & 15, l4 = lane >> 4;

    const int orig = blockIdx.x;
    const int blk = (orig & 7) * 96 + (orig >> 3);  // 768 = 8*96, bijective
    const int b = blk / 24;
    const int c = kOrder[blk % 24];      // exact LPT: longest chains first
    int qt, ch, nch;                     // chunk decode (24 chunks per batch)
    if (c < 8) { qt = c;                ch = 0;           nch = 1; }
    else       { qt = 8 + ((c - 8) >> 1); ch = (c - 8) & 1; nch = 2; }
    const int q0 = qt * 64;
    const int t0 = ch * 8;
    const int t1 = min(t0 + 8, qt + 1);

    // Q fragments (B-operand), scale pre-folded
    const unsigned short* qp = qg + ((size_t)(b * SEQ + q0 + w * 16 + l15)) * DIM + l4 * 8;
    const bf16x8 qf0 = *(const bf16x8*)qp;
    const bf16x8 qf1 = *(const bf16x8*)(qp + 32);

    // DMA staging: lane l of wave w covers stored row w*16+i*8+(l>>3),
    // stored chunk l&7. Inverse-swizzled global chunk = (l&7)^(l>>3).
    const int lrow = lane >> 3;
    const int gch  = (lane & 7) ^ lrow;
    const unsigned short* kgl0 = kg + (size_t)b * SEQ * DIM
                               + (size_t)(w * 16 + lrow) * DIM + gch * 8;
    const unsigned short* kgl1 = kgl0 + (size_t)8 * DIM;
    const unsigned short* vgl0 = vtg + ((size_t)b * 64 + w * 16 + lrow) * SEQ + gch * 8;
    const unsigned short* vgl1 = vgl0 + (size_t)8 * SEQ;
    const int ldsb0 = (w * 16) * 64;
    const int ldsb1 = (w * 16 + 8) * 64;

    // read-side swizzled chunk offset (row&7 == l15&7 for all frag rows)
    const int rc0 = (l4 ^ (l15 & 7)) << 3;

    // prologue: DMA tile t0 into buffer 0
    {
        const size_t ko = (size_t)t0 * 64 * DIM;
        const size_t vo = (size_t)t0 * 64;
        GLL(kgl0 + ko, &Ks[0][ldsb0]);
        GLL(kgl1 + ko, &Ks[0][ldsb1]);
        GLL(vgl0 + vo, &Vs[0][ldsb0]);
        GLL(vgl1 + vo, &Vs[0][ldsb1]);
    }
    __syncthreads();   // drains vmcnt: tile t0 resident

    f32x4 acc[4] = {};
    float m_run = -1e30f;   // running max (uniform across the l4 group)
    float l_part = 0.f;     // per-lane partial of l (own 16 k-values)

    for (int tt = t0; tt < t1; ++tt) {
        const int cur = (tt - t0) & 1;
        const bool pf = (tt + 1 < t1);
        if (pf) {  // fire-and-forget DMA for t+1; lands during this tile
            const size_t ko = (size_t)(tt + 1) * 64 * DIM;
            const size_t vo = (size_t)(tt + 1) * 64;
            const int nxt = cur ^ 1;
            GLL(kgl0 + ko, &Ks[nxt][ldsb0]);
            GLL(kgl1 + ko, &Ks[nxt][ldsb1]);
            GLL(vgl0 + vo, &Vs[nxt][ldsb0]);
            GLL(vgl1 + vo, &Vs[nxt][ldsb1]);
        }

        // S^T = K . Q : lane holds S[k=nb*16+l4*4+r][q=l15]
        f32x4 s[4];
        __builtin_amdgcn_s_setprio(1);
        #pragma unroll
        for (int nb = 0; nb < 4; ++nb) {
            const int krow = (nb * 16 + l15) * 64;
            const bf16x8 kf0 = *(const bf16x8*)&Ks[cur][krow + rc0];
            const bf16x8 kf1 = *(const bf16x8*)&Ks[cur][krow + (rc0 ^ 32)];
            f32x4 sv = {0.f, 0.f, 0.f, 0.f};
            sv = MFMA16(kf0, qf0, sv, 0, 0, 0);
            sv = MFMA16(kf1, qf1, sv, 0, 0, 0);
            s[nb] = sv;
        }
        __builtin_amdgcn_s_setprio(0);

        if (tt == qt) {  // causal mask on diagonal tile
            const int qabs = q0 + w * 16 + l15;
            #pragma unroll
            for (int nb = 0; nb < 4; ++nb)
                #pragma unroll
                for (int r = 0; r < 4; ++r)
                    if (tt * 64 + nb * 16 + l4 * 4 + r > qabs) s[nb][r] = -1e30f;
        }

        // local pmax (this lane's 16 values) -- pure tree, no shfl
        float pmax = fmaxf(fmaxf(fmaxf(s[0][0], s[0][1]), fmaxf(s[0][2], s[0][3])),
                           fmaxf(fmaxf(s[1][0], s[1][1]), fmaxf(s[1][2], s[1][3])));
        pmax = fmaxf(pmax,
               fmaxf(fmaxf(fmaxf(s[2][0], s[2][1]), fmaxf(s[2][2], s[2][3])),
                     fmaxf(fmaxf(s[3][0], s[3][1]), fmaxf(s[3][2], s[3][3]))));

        // defer-max (T13): rescale only when some lane's local max grew past
        // THR. Butterfly to the true row max only inside the rare branch.
        if (!__all(pmax - m_run <= DEFER_THR)) {
            pmax = fmaxf(pmax, __shfl_xor(pmax, 16));
            pmax = fmaxf(pmax, __shfl_xor(pmax, 32));
            const float mnew = fmaxf(m_run, pmax);
            const float scf = __expf(m_run - mnew);
            m_run = mnew;
            l_part *= scf;
            #pragma unroll
            for (int r = 0; r < 4; ++r) {  // acc row r = q-row l4*4+r
                const float srw = __shfl(scf, l4 * 4 + r);
                acc[0][r] *= srw; acc[1][r] *= srw;
                acc[2][r] *= srw; acc[3][r] *= srw;
            }
        }

        #pragma unroll
        for (int nb = 0; nb < 4; ++nb)
            #pragma unroll
            for (int r = 0; r < 4; ++r) {
                s[nb][r] = __expf(s[nb][r] - m_run);
                l_part += s[nb][r];
            }

        // P -> swizzled wave-private LDS (b64), then A-frag readback
        const int psbase = l15 * 64 + (l4 & 1) * 4;
        const int pch = l4 >> 1;
        #pragma unroll
        for (int nb = 0; nb < 4; ++nb) {
            const ull v = (ull)pk2(s[nb][0], s[nb][1]) |
                          ((ull)pk2(s[nb][2], s[nb][3]) << 32);
            *(ull*)&Ps[w][psbase + (((2 * nb + pch) ^ (l15 & 7)) << 3)] = v;
        }
        const bf16x8 pa0 = *(const bf16x8*)&Ps[w][l15 * 64 + rc0];
        const bf16x8 pa1 = *(const bf16x8*)&Ps[w][l15 * 64 + (rc0 ^ 32)];

        __builtin_amdgcn_s_setprio(1);
        #pragma unroll
        for (int nb2 = 0; nb2 < 4; ++nb2) {
            const int vrow = (nb2 * 16 + l15) * 64;
            const bf16x8 vb0 = *(const bf16x8*)&Vs[cur][vrow + rc0];
            const bf16x8 vb1 = *(const bf16x8*)&Vs[cur][vrow + (rc0 ^ 32)];
            acc[nb2] = MFMA16(pa0, vb0, acc[nb2], 0, 0, 0);
            acc[nb2] = MFMA16(pa1, vb1, acc[nb2], 0, 0, 0);
        }
        __builtin_amdgcn_s_setprio(0);

        __syncthreads();  // single barrier per tile; also drains t+1 DMA
    }

    // finalize l: butterfly the per-lane partials once (uniform across l4)
    float l_run = l_part;
    l_run += __shfl_xor(l_run, 16);
    l_run += __shfl_xor(l_run, 32);

    if (nch == 1) {  // qt <= 7: full k-range done here, write final output
        const float inv = 1.0f / l_run;
        #pragma unroll
        for (int r = 0; r < 4; ++r) {
            const float ir = __shfl(inv, l4 * 4 + r);
            const size_t row = (size_t)(b * SEQ + q0 + w * 16 + l4 * 4 + r);
            #pragma unroll
            for (int nb2 = 0; nb2 < 4; ++nb2)
                out[row * DIM + nb2 * 16 + l15] = acc[nb2][r] * ir;
        }
    } else {         // lane-native partial: 2 coalesced bf16x8 stores
        const size_t slot = (size_t)((b * 8 + (qt - 8)) * 2 + ch);
        unsigned short* pa = part_acc + slot * 4096 + (size_t)(w * 64 + lane) * 16;
        bf16x8 o0, o1;
        #pragma unroll
        for (int nb2 = 0; nb2 < 2; ++nb2)
            #pragma unroll
            for (int r = 0; r < 4; ++r) {
                o0[nb2 * 4 + r] = (short)f2bf(acc[nb2][r]);
                o1[nb2 * 4 + r] = (short)f2bf(acc[nb2 + 2][r]);
            }
        *(bf16x8*)pa       = o0;
        *(bf16x8*)(pa + 8) = o1;
        if (l4 == 0) {
            float* pm = part_ml + slot * 128;
            pm[w * 16 + l15]      = m_run;
            pm[64 + w * 16 + l15] = l_run;
        }
    }
}

// ---------------- Kernel 3: split-K combine (qt >= 8, exactly 2 chunks) ----
__global__ __launch_bounds__(256) void combine(
    const unsigned short* __restrict__ part_acc,
    const float* __restrict__ part_ml, float* __restrict__ out)
{
    const int orig = blockIdx.x;
    const int blk = (orig & 7) * 32 + (orig >> 3);   // 256 = 8*32, bijective
    const int b = blk / 8, qt8 = blk % 8;
    const int qt = qt8 + 8;
    const int tid = threadIdx.x;
    const int w2 = tid >> 6, lane = tid & 63;
    const int l15 = lane & 15, l4 = lane >> 4;
    const size_t base0 = (size_t)(b * 8 + qt8) * 2;

    float mv[2][4], lv[2][4], M[4];
    #pragma unroll
    for (int cc = 0; cc < 2; ++cc) {
        const float* pm = part_ml + (base0 + cc) * 128;
        #pragma unroll
        for (int r = 0; r < 4; ++r) {
            mv[cc][r] = pm[w2 * 16 + l4 * 4 + r];
            lv[cc][r] = pm[64 + w2 * 16 + l4 * 4 + r];
        }
    }
    #pragma unroll
    for (int r = 0; r < 4; ++r) M[r] = fmaxf(mv[0][r], mv[1][r]);

    float o[16], L[4];
    #pragma unroll
    for (int i = 0; i < 16; ++i) o[i] = 0.f;
    #pragma unroll
    for (int r = 0; r < 4; ++r) L[r] = 0.f;
    #pragma unroll
    for (int cc = 0; cc < 2; ++cc) {
        float wsc[4];
        #pragma unroll
        for (int r = 0; r < 4; ++r) {
            wsc[r] = __expf(mv[cc][r] - M[r]);
            L[r] += wsc[r] * lv[cc][r];
        }
        const unsigned short* pa =
            part_acc + (base0 + cc) * 4096 + (size_t)(w2 * 64 + lane) * 16;
        const ushort8 t0 = *(const ushort8*)pa;
        const ushort8 t1 = *(const ushort8*)(pa + 8);
        #pragma unroll
        for (int i = 0; i < 8; ++i) {
            o[i]     += wsc[i & 3] * bf2f(t0[i]);
            o[i + 8] += wsc[i & 3] * bf2f(t1[i]);
        }
    }
    float inv[4];
    #pragma unroll
    for (int r = 0; r < 4; ++r) inv[r] = 1.0f / L[r];
    #pragma unroll
    for (int nb2 = 0; nb2 < 4; ++nb2)
        #pragma unroll
        for (int r = 0; r < 4; ++r) {
            const size_t row = (size_t)(b * SEQ + qt * 64 + w2 * 16 + l4 * 4 + r);
            out[row * DIM + nb2 * 16 + l15] = o[nb2 * 4 + r] * inv[r];
        }
}

extern "C" void kernel_launch(void* const* d_in, const int* in_sizes, int n_in,
                              void* d_out, int out_size, void* d_ws, size_t ws_size,
                              hipStream_t stream) {
    const float* x  = (const float*)d_in[0];
    const float* Wq = (const float*)d_in[1];
    const float* Wk = (const float*)d_in[2];
    const float* Wv = (const float*)d_in[3];
    float* outp = (float*)d_out;

    // ws: q | k | vT (bf16, 4MB each) | part_acc (bf16, 4.2MB) | part_ml (fp32)
    unsigned short* qw  = (unsigned short*)d_ws;
    unsigned short* kw  = qw + (size_t)NB * SEQ * DIM;
    unsigned short* vtw = kw + (size_t)NB * SEQ * DIM;
    unsigned short* pacc = vtw + (size_t)NB * SEQ * DIM;
    float* pml = (float*)(pacc + (size_t)NB * 8 * 2 * 4096);

    qkv_proj<<<NB * SEQ / 64, 256, 0, stream>>>(x, Wq, Wk, Wv, qw, kw, vtw);
    attn_partial<<<NB * 24, 256, 0, stream>>>(qw, kw, vtw, outp, pacc, pml);
    combine<<<NB * 8, 256, 0, stream>>>(pacc, pml, outp);
}